// Round 6
// baseline (198.241 us; speedup 1.0000x reference)
//
#include <hip/hip_runtime.h>

#define N 4096
#define D 256
#define MARGIN 0.3f
#define BIG 10000.0f

typedef _Float16 f16x8 __attribute__((ext_vector_type(8)));
typedef _Float16 f16x4 __attribute__((ext_vector_type(4)));
typedef float floatx16 __attribute__((ext_vector_type(16)));

__device__ inline void atomicMaxFloatPos(float* a, float v) {
    atomicMax((int*)a, __float_as_int(v));   // valid: all values >= 0
}
__device__ inline void atomicMinFloatPos(float* a, float v) {
    atomicMin((int*)a, __float_as_int(v));
}

// async 16B global -> LDS (wave-uniform LDS base + lane*16)
__device__ inline void gl_lds16(const void* g, void* l) {
    __builtin_amdgcn_global_load_lds(
        (const __attribute__((address_space(1))) unsigned int*)g,
        (__attribute__((address_space(3))) unsigned int*)l, 16, 0, 0);
}

// Wave per row: convert x -> fp16 Xf (RNE, row-major), sq from the CONVERTED
// values (so the Gram diagonal cancels exactly), init ap/ang/anl.
__global__ __launch_bounds__(256) void prep_kernel(const float* __restrict__ x,
                                                   float* __restrict__ sq,
                                                   _Float16* __restrict__ Xf,
                                                   float* ap, float* ang, float* anl) {
    const int wave = threadIdx.x >> 6, lane = threadIdx.x & 63;
    const int row = blockIdx.x * 4 + wave;
    const float4 v = *(const float4*)(x + (size_t)row * D + lane * 4);
    f16x4 h;
    h[0] = (_Float16)v.x; h[1] = (_Float16)v.y;
    h[2] = (_Float16)v.z; h[3] = (_Float16)v.w;
    *(f16x4*)(Xf + (size_t)row * D + lane * 4) = h;
    const float c0 = (float)h[0], c1 = (float)h[1], c2 = (float)h[2], c3 = (float)h[3];
    float s = c0 * c0 + c1 * c1 + c2 * c2 + c3 * c3;
    #pragma unroll
    for (int off = 32; off; off >>= 1) s += __shfl_down(s, off);
    if (lane == 0) sq[row] = s;
    if (threadIdx.x < 4) {
        const int i = blockIdx.x * 4 + threadIdx.x;
        ap[i] = 0.0f; ang[i] = BIG; anl[i] = BIG;
    }
}

// dist v7: SYMMETRY — only the 528 upper-triangle 128x128 tiles (by <= bx)
// are computed (vs 1024): MFMA work and staging both halve. K-loop is the
// proven v4 structure: 4 waves, 32 KB single-buffered LDS, 4 stages of BK=64,
// vmcnt(0)+barrier per stage, cross-block overlap from ~4 blocks/CU.
// Off-diagonal tiles write the direct block (coalesced) AND the mirrored
// block dist[c][r]: each wave transposes its 64x64 sub-tile through its
// PRIVATE 8 KB slice of the (dead) staging LDS in two 32x64 chunks,
// XOR-swizzled T[r][(c^r)&63] (conflict-free writes and reads, no barriers).
// Reduction: column-anchored reduce on acc (anchors = cols, labels = rows)
// plus, for off-diag tiles, the same reduce on the transposed copy
// (anchors = rows, labels = cols). Duplicated pairs are harmless: min/max
// atomics are idempotent. Mirrored values are bit-identical to computed ones.
__global__ __launch_bounds__(256, 4) void dist_kernel(const _Float16* __restrict__ Xf,
                                                      const int* __restrict__ tgt,
                                                      const float* __restrict__ sq,
                                                      float* __restrict__ dist,
                                                      float* ap, float* ang, float* anl) {
    __shared__ _Float16 lds[16384];         // 32 KiB: staging A[0..8191], B[8192..16383]

    const int tid  = threadIdx.x;
    const int wv   = tid >> 6;
    const int lane = tid & 63;

    // triangular decode: idx -> (by <= bx), idx = bx*(bx+1)/2 + by
    const int idx = blockIdx.x;
    int bx = (int)((sqrtf(8.0f * (float)idx + 1.0f) - 1.0f) * 0.5f);
    while ((bx + 1) * (bx + 2) / 2 <= idx) ++bx;
    while (bx * (bx + 1) / 2 > idx) --bx;
    const int by = idx - bx * (bx + 1) / 2;
    const int row0 = by * 128;
    const int col0 = bx * 128;
    const bool diag = (by == bx);

    const int wr = wv >> 1, wc = wv & 1;

    // DMA mapping (v4): instr d of wave wv covers panel rows ((wv&1)*64+d*8..+7).
    // lane: g = lane>>3 (row in 8-group), p = lane&7 (phys quad); fetch
    // logical quad lq = p ^ g (row&7 == g since row-base is a multiple of 8).
    const int g = lane >> 3, p = lane & 7, lq = p ^ g;
    const int selrow = (wv < 2 ? row0 : col0) + (wv & 1) * 64 + g;
    const _Float16* src0 = Xf + (size_t)selrow * D + lq * 8;
    _Float16* dst0 = lds + wv * 8 * 512;

    // Epilogue scalars prefetched (latency hides under K-loop).
    const int m0 = lane & 31;
    const int hi = lane >> 5;
    const int sw = m0 & 7;
    const int rowbase = row0 + wr * 64;
    const int colbase = col0 + wc * 64;
    const int tl  = tgt[rowbase + lane];
    const int tcl = tgt[colbase + lane];
    const float sq_r = sq[rowbase + lane];
    const unsigned long long pb_0 = __ballot(tl & 1);
    const unsigned long long pb_1 = __ballot(tl & 2);
    const unsigned long long pc_0 = __ballot(tcl & 1);
    const unsigned long long pc_1 = __ballot(tcl & 2);
    const int gc0 = colbase + m0, gc1 = colbase + 32 + m0;
    const int tc0 = tgt[gc0], tc1 = tgt[gc1];
    const float sqc0 = sq[gc0], sqc1 = sq[gc1];

    floatx16 acc[2][2];
    #pragma unroll
    for (int mt = 0; mt < 2; ++mt)
        #pragma unroll
        for (int nt = 0; nt < 2; ++nt)
            #pragma unroll
            for (int r = 0; r < 16; ++r) acc[mt][nt][r] = 0.0f;

    const _Float16* ldsA0 = lds + (wr * 64 + m0) * 64;
    const _Float16* ldsA1 = lds + (wr * 64 + 32 + m0) * 64;
    const _Float16* ldsB0 = lds + 8192 + (wc * 64 + m0) * 64;
    const _Float16* ldsB1 = lds + 8192 + (wc * 64 + 32 + m0) * 64;

    #pragma unroll
    for (int s = 0; s < 4; ++s) {
        if (s) {    // all waves' frag reads of stage s-1 must retire first
            __asm__ volatile("s_waitcnt lgkmcnt(0)" ::: "memory");
            __builtin_amdgcn_s_barrier();
        }
        const int k0 = s * 64;
        #pragma unroll
        for (int d = 0; d < 8; ++d)
            gl_lds16(src0 + (size_t)d * 8 * D + k0, dst0 + d * 512);
        __asm__ volatile("s_waitcnt vmcnt(0)" ::: "memory");
        __builtin_amdgcn_s_barrier();

        __builtin_amdgcn_s_setprio(1);
        #pragma unroll
        for (int ks = 0; ks < 4; ++ks) {
            const int la = ks * 2 + hi;                 // logical quad 0..7
            const int po = (la ^ sw) << 3;
            f16x8 a0 = *(const f16x8*)(ldsA0 + po);
            f16x8 a1 = *(const f16x8*)(ldsA1 + po);
            f16x8 b0 = *(const f16x8*)(ldsB0 + po);
            f16x8 b1 = *(const f16x8*)(ldsB1 + po);
            acc[0][0] = __builtin_amdgcn_mfma_f32_32x32x16_f16(a0, b0, acc[0][0], 0, 0, 0);
            acc[0][1] = __builtin_amdgcn_mfma_f32_32x32x16_f16(a0, b1, acc[0][1], 0, 0, 0);
            acc[1][0] = __builtin_amdgcn_mfma_f32_32x32x16_f16(a1, b0, acc[1][0], 0, 0, 0);
            acc[1][1] = __builtin_amdgcn_mfma_f32_32x32x16_f16(a1, b1, acc[1][1], 0, 0, 0);
        }
        __builtin_amdgcn_s_setprio(0);
        __asm__ volatile("" ::: "memory");   // pin stage ordering
    }

    // ---- Epilogue. C layout: col = lane&31 (+32*nt),
    // row = (r&3) + 8*(r>>2) + 4*hi + 32*mt.
    const int rl_base = 4 * hi;
    float* Tph = (float*)lds + wv * 2048;   // wave-private 8 KB slice (32x64 f32)

    if (!diag) {   // staging LDS is about to be reused; all waves must be done
        __asm__ volatile("s_waitcnt lgkmcnt(0)" ::: "memory");
        __builtin_amdgcn_s_barrier();
    }

    float mx0 = 0.0f, mg0 = BIG, ml0 = BIG;
    float mx1 = 0.0f, mg1 = BIG, ml1 = BIG;

    #pragma unroll
    for (int mt = 0; mt < 2; ++mt) {
        // ---- phase A: compute d, direct stores, col-anchored reduce,
        // and (off-diag) stash chunk mt (rows 32mt..32mt+31) into Tph.
        #pragma unroll
        for (int r = 0; r < 16; ++r) {
            const int row_l = mt * 32 + (r & 3) + 8 * (r >> 2) + rl_base;
            const int grow  = rowbase + row_l;
            const float sqi = __shfl(sq_r, row_l);
            const float d0 = sqrtf(fmaxf(sqi + sqc0 - 2.0f * acc[mt][0][r], 0.0f));
            const float d1 = sqrtf(fmaxf(sqi + sqc1 - 2.0f * acc[mt][1][r], 0.0f));
            __builtin_nontemporal_store(d0, dist + (size_t)grow * N + gc0);
            __builtin_nontemporal_store(d1, dist + (size_t)grow * N + gc1);
            const int tr = (int)((pb_0 >> row_l) & 1) | ((int)((pb_1 >> row_l) & 1) << 1);
            mx0 = fmaxf(mx0, (tr == tc0) ? d0 : 0.0f);
            mg0 = fminf(mg0, (tr >  tc0) ? d0 : BIG);
            ml0 = fminf(ml0, (tr <  tc0) ? d0 : BIG);
            mx1 = fmaxf(mx1, (tr == tc1) ? d1 : 0.0f);
            mg1 = fminf(mg1, (tr >  tc1) ? d1 : BIG);
            ml1 = fminf(ml1, (tr <  tc1) ? d1 : BIG);
            if (!diag) {
                const int rr = row_l & 31;              // row within chunk
                Tph[rr * 64 + ((m0 ^ rr) & 63)]        = d0;
                Tph[rr * 64 + (((32 + m0) ^ rr) & 63)] = d1;
            }
        }
        // ---- phase B (off-diag): mirrored stores + row-anchored reduce for
        // anchors rowbase + 32*mt + m0 (this chunk's original rows).
        if (!diag) {
            float mxT = 0.0f, mgT = BIG, mlT = BIG;
            const int tra = __shfl(tl, mt * 32 + m0);   // anchor label
            #pragma unroll
            for (int mtc = 0; mtc < 2; ++mtc) {
                #pragma unroll
                for (int r = 0; r < 16; ++r) {
                    const int crow = mtc * 32 + (r & 3) + 8 * (r >> 2) + rl_base; // col 0..63
                    const float v = Tph[m0 * 64 + ((crow ^ m0) & 63)]; // d(32mt+m0, crow)
                    __builtin_nontemporal_store(
                        v, dist + (size_t)(colbase + crow) * N + rowbase + mt * 32 + m0);
                    const int tcr = (int)((pc_0 >> crow) & 1) | ((int)((pc_1 >> crow) & 1) << 1);
                    mxT = fmaxf(mxT, (tcr == tra) ? v : 0.0f);
                    mgT = fminf(mgT, (tcr >  tra) ? v : BIG);
                    mlT = fminf(mlT, (tcr <  tra) ? v : BIG);
                }
            }
            mxT = fmaxf(mxT, __shfl_xor(mxT, 32));
            mgT = fminf(mgT, __shfl_xor(mgT, 32));
            mlT = fminf(mlT, __shfl_xor(mlT, 32));
            if (hi == 0) {
                const int a = rowbase + mt * 32 + m0;
                atomicMaxFloatPos(&ap[a],  mxT);
                atomicMinFloatPos(&ang[a], mgT);
                atomicMinFloatPos(&anl[a], mlT);
            }
        }
    }
    // combine the two hi-halves of the column-anchored reduce
    mx0 = fmaxf(mx0, __shfl_xor(mx0, 32));
    mg0 = fminf(mg0, __shfl_xor(mg0, 32));
    ml0 = fminf(ml0, __shfl_xor(ml0, 32));
    mx1 = fmaxf(mx1, __shfl_xor(mx1, 32));
    mg1 = fminf(mg1, __shfl_xor(mg1, 32));
    ml1 = fminf(ml1, __shfl_xor(ml1, 32));

    if (hi == 0) {
        atomicMaxFloatPos(&ap[gc0],  mx0);
        atomicMinFloatPos(&ang[gc0], mg0);
        atomicMinFloatPos(&anl[gc0], ml0);
        atomicMaxFloatPos(&ap[gc1],  mx1);
        atomicMinFloatPos(&ang[gc1], mg1);
        atomicMinFloatPos(&anl[gc1], ml1);
    }
}

// One block: histogram (packed wave reduce), then loss/cnt, write outputs.
__global__ __launch_bounds__(1024) void finish_kernel(const float* __restrict__ ap,
                                                      const float* __restrict__ ang,
                                                      const float* __restrict__ anl,
                                                      const int* __restrict__ tgt,
                                                      float* __restrict__ out) {
    __shared__ int hist[4];
    __shared__ unsigned hsum[2][16];
    __shared__ float wsum[16];
    __shared__ int wcnt[16];
    const int tid = threadIdx.x, lane = tid & 63, wv = tid >> 6;

    const int4 t4 = *(const int4*)&tgt[tid * 4];
    int c[4] = {0, 0, 0, 0};
    c[t4.x & 3]++; c[t4.y & 3]++; c[t4.z & 3]++; c[t4.w & 3]++;
    unsigned p01 = (unsigned)c[0] | ((unsigned)c[1] << 16);
    unsigned p23 = (unsigned)c[2] | ((unsigned)c[3] << 16);
    #pragma unroll
    for (int off = 32; off; off >>= 1) {
        p01 += __shfl_down(p01, off);
        p23 += __shfl_down(p23, off);
    }
    if (lane == 0) { hsum[0][wv] = p01; hsum[1][wv] = p23; }
    __syncthreads();
    if (tid == 0) {
        unsigned a = 0, b = 0;
        for (int i = 0; i < 16; ++i) { a += hsum[0][i]; b += hsum[1][i]; }
        hist[0] = a & 0xFFFF; hist[1] = a >> 16;
        hist[2] = b & 0xFFFF; hist[3] = b >> 16;
    }
    __syncthreads();

    float term = 0.0f; int cc = 0;
    const int lab[4] = {t4.x & 3, t4.y & 3, t4.z & 3, t4.w & 3};
    #pragma unroll
    for (int j = 0; j < 4; ++j) {
        const int i = tid * 4 + j;
        term += fmaxf(ap[i] - fabsf(ang[i] - anl[i]) + MARGIN, 0.0f);
        cc += (hist[lab[j]] == 1) ? 1 : 0;
    }
    #pragma unroll
    for (int off = 32; off; off >>= 1) {
        term += __shfl_down(term, off);
        cc   += __shfl_down(cc, off);
    }
    if (lane == 0) { wsum[wv] = term; wcnt[wv] = cc; }
    __syncthreads();
    if (tid == 0) {
        float ls = 0.0f; int cs = 0;
        for (int i = 0; i < 16; ++i) { ls += wsum[i]; cs += wcnt[i]; }
        out[0] = ls * (1.0f / N);
        out[1 + (size_t)N * N] = (float)cs;
    }
}

extern "C" void kernel_launch(void* const* d_in, const int* in_sizes, int n_in,
                              void* d_out, int out_size, void* d_ws, size_t ws_size,
                              hipStream_t stream) {
    const float* x   = (const float*)d_in[0];
    const int*   tgt = (const int*)d_in[1];
    float* out = (float*)d_out;
    char*  ws  = (char*)d_ws;

    _Float16* Xf  = (_Float16*)ws;                    // 2 MiB, 16B-aligned
    float*    sq  = (float*)(ws + 2097152);
    float*    ap  = sq + 4096;
    float*    ang = sq + 8192;
    float*    anl = sq + 12288;

    prep_kernel<<<N / 4, 256, 0, stream>>>(x, sq, Xf, ap, ang, anl);
    const int ntiles = (N / 128) * (N / 128 + 1) / 2;   // 528 upper-triangle tiles
    dist_kernel<<<ntiles, 256, 0, stream>>>(Xf, tgt, sq, out + 1, ap, ang, anl);
    finish_kernel<<<1, 1024, 0, stream>>>(ap, ang, anl, tgt, out);
}

// Round 7
// 111.389 us; speedup vs baseline: 1.7797x; 1.7797x over previous
//
#include <hip/hip_runtime.h>

#define N 4096
#define D 256
#define MARGIN 0.3f
#define BIG 10000.0f

typedef _Float16 f16x8 __attribute__((ext_vector_type(8)));
typedef _Float16 f16x4 __attribute__((ext_vector_type(4)));
typedef float floatx16 __attribute__((ext_vector_type(16)));

__device__ inline void atomicMaxFloatPos(float* a, float v) {
    atomicMax((int*)a, __float_as_int(v));   // valid: all values >= 0
}
__device__ inline void atomicMinFloatPos(float* a, float v) {
    atomicMin((int*)a, __float_as_int(v));
}

// async 16B global -> LDS (wave-uniform LDS base + lane*16)
__device__ inline void gl_lds16(const void* g, void* l) {
    __builtin_amdgcn_global_load_lds(
        (const __attribute__((address_space(1))) unsigned int*)g,
        (__attribute__((address_space(3))) unsigned int*)l, 16, 0, 0);
}

// Wave per row: convert x -> fp16 Xf (RNE, row-major), sq from the CONVERTED
// values (so the Gram diagonal cancels exactly), init ap/ang/anl.
__global__ __launch_bounds__(256) void prep_kernel(const float* __restrict__ x,
                                                   float* __restrict__ sq,
                                                   _Float16* __restrict__ Xf,
                                                   float* ap, float* ang, float* anl) {
    const int wave = threadIdx.x >> 6, lane = threadIdx.x & 63;
    const int row = blockIdx.x * 4 + wave;
    const float4 v = *(const float4*)(x + (size_t)row * D + lane * 4);
    f16x4 h;
    h[0] = (_Float16)v.x; h[1] = (_Float16)v.y;
    h[2] = (_Float16)v.z; h[3] = (_Float16)v.w;
    *(f16x4*)(Xf + (size_t)row * D + lane * 4) = h;
    const float c0 = (float)h[0], c1 = (float)h[1], c2 = (float)h[2], c3 = (float)h[3];
    float s = c0 * c0 + c1 * c1 + c2 * c2 + c3 * c3;
    #pragma unroll
    for (int off = 32; off; off >>= 1) s += __shfl_down(s, off);
    if (lane == 0) sq[row] = s;
    if (threadIdx.x < 4) {
        const int i = blockIdx.x * 4 + threadIdx.x;
        ap[i] = 0.0f; ang[i] = BIG; anl[i] = BIG;
    }
}

// dist v8: 8 waves (512 thr) per 128x256 tile. Rationale (R6 post-mortem):
// v6's 256^2/128KB-LDS forced exactly 1 block/CU (grid 256, LDS cap) -> the
// DMA-bound K-loop and store-bound epilogue SERIALIZE with nothing to overlap
// them. Here: grid 512 (2/CU avg), LDS 48 KB single-buffered (3 blocks/CU
// fit) -> one block's epilogue overlaps another's K-loop; staging totals
// 98 MB (vs v4's 134).
// LDS: A panel 128 rows x 64 fp16 at 0 (16 KB), B panel 256 rows x 64 fp16
// at +8192 elems (32 KB). 128 B rows; 16B quad l of row r stored at phys
// quad l ^ (r&7) (proven conflict-free b128 scheme). 4 stages of BK=64,
// vmcnt(0)+barrier per stage (v4 structure, proven): each wave issues 6
// gl_lds16 (row-group rg = wv*6+d; rg<16 -> A group rg, else B group rg-16).
// Wave (wr,wc) = (wv>>2, wv&3) owns a 64x64 sub-tile -> acc[2][2] (~64 VGPR).
// Epilogue: NO LDS. anchor = column (valid by symmetry); row labels from two
// __ballot packs; sqi via register + __shfl; hi-halves combined with
// __shfl_xor(32); 6 atomics from lanes 0..31. Direct (row-banded) coalesced
// nontemporal stores ONLY - R6 proved mirrored stores destroy write combining.
__global__ __launch_bounds__(512, 4) void dist_kernel(const _Float16* __restrict__ Xf,
                                                      const int* __restrict__ tgt,
                                                      const float* __restrict__ sq,
                                                      float* __restrict__ dist,
                                                      float* ap, float* ang, float* anl) {
    __shared__ _Float16 lds[24576];         // 48 KiB: A[0..8191], B[8192..24575]

    const int tid  = threadIdx.x;
    const int wv   = tid >> 6;              // 0..7
    const int lane = tid & 63;
    const int row0 = blockIdx.y * 128;
    const int col0 = blockIdx.x * 256;
    const int wr = wv >> 2, wc = wv & 3;

    // DMA mapping: row-group rg = wv*6 + d (48 groups of 8 rows, 1 KB each).
    // lane: g = lane>>3 (row in 8-group), p = lane&7 (phys quad); fetch
    // logical quad lq = p ^ g (row&7 == g since group base is a multiple of 8).
    const int g = lane >> 3, p = lane & 7, lq = p ^ g;

    // Epilogue scalars prefetched (latency hides under K-loop).
    const int m0 = lane & 31;
    const int hi = lane >> 5;
    const int sw = m0 & 7;                   // frag swizzle key
    const int rowbase = row0 + wr * 64;
    const int colbase = col0 + wc * 64;
    const int tl = tgt[rowbase + lane];
    const float sq_r = sq[rowbase + lane];
    const unsigned long long pb_0 = __ballot(tl & 1);
    const unsigned long long pb_1 = __ballot(tl & 2);
    const int gc0 = colbase + m0, gc1 = colbase + 32 + m0;
    const int tc0 = tgt[gc0], tc1 = tgt[gc1];
    const float sqc0 = sq[gc0], sqc1 = sq[gc1];

    floatx16 acc[2][2];
    #pragma unroll
    for (int mt = 0; mt < 2; ++mt)
        #pragma unroll
        for (int nt = 0; nt < 2; ++nt)
            #pragma unroll
            for (int r = 0; r < 16; ++r) acc[mt][nt][r] = 0.0f;

    const _Float16* ldsA0 = lds + (wr * 64 + m0) * 64;
    const _Float16* ldsA1 = lds + (wr * 64 + 32 + m0) * 64;
    const _Float16* ldsB0 = lds + 8192 + (wc * 64 + m0) * 64;
    const _Float16* ldsB1 = lds + 8192 + (wc * 64 + 32 + m0) * 64;

    #pragma unroll
    for (int s = 0; s < 4; ++s) {
        if (s) {    // all waves' frag reads of stage s-1 must retire first
            __asm__ volatile("s_waitcnt lgkmcnt(0)" ::: "memory");
            __builtin_amdgcn_s_barrier();
        }
        const int k0 = s * 64;
        #pragma unroll
        for (int d = 0; d < 6; ++d) {
            const int rg = wv * 6 + d;
            const int prow = (rg < 16) ? (row0 + rg * 8 + g)
                                       : (col0 + (rg - 16) * 8 + g);
            gl_lds16(Xf + (size_t)prow * D + k0 + lq * 8, lds + rg * 512);
        }
        __asm__ volatile("s_waitcnt vmcnt(0)" ::: "memory");
        __builtin_amdgcn_s_barrier();

        __builtin_amdgcn_s_setprio(1);
        #pragma unroll
        for (int ks = 0; ks < 4; ++ks) {
            const int la = ks * 2 + hi;                 // logical quad 0..7
            const int po = (la ^ sw) << 3;
            f16x8 a0 = *(const f16x8*)(ldsA0 + po);
            f16x8 a1 = *(const f16x8*)(ldsA1 + po);
            f16x8 b0 = *(const f16x8*)(ldsB0 + po);
            f16x8 b1 = *(const f16x8*)(ldsB1 + po);
            acc[0][0] = __builtin_amdgcn_mfma_f32_32x32x16_f16(a0, b0, acc[0][0], 0, 0, 0);
            acc[0][1] = __builtin_amdgcn_mfma_f32_32x32x16_f16(a0, b1, acc[0][1], 0, 0, 0);
            acc[1][0] = __builtin_amdgcn_mfma_f32_32x32x16_f16(a1, b0, acc[1][0], 0, 0, 0);
            acc[1][1] = __builtin_amdgcn_mfma_f32_32x32x16_f16(a1, b1, acc[1][1], 0, 0, 0);
        }
        __builtin_amdgcn_s_setprio(0);
        __asm__ volatile("" ::: "memory");   // pin stage ordering
    }

    // ---- Epilogue: d = sqrt(sqi + sqj - 2*dot); nontemporal coalesced global
    // stores; in-register column reduction (anchor = column).
    // C layout: col = lane&31 (+32*nt), row = (r&3) + 8*(r>>2) + 4*hi + 32*mt.
    const int rl_base = 4 * hi;

    float mx0 = 0.0f, mg0 = BIG, ml0 = BIG;
    float mx1 = 0.0f, mg1 = BIG, ml1 = BIG;

    #pragma unroll
    for (int mt = 0; mt < 2; ++mt) {
        #pragma unroll
        for (int r = 0; r < 16; ++r) {
            const int row_l = mt * 32 + (r & 3) + 8 * (r >> 2) + rl_base;
            const int grow  = rowbase + row_l;
            const float sqi = __shfl(sq_r, row_l);
            const float d0 = sqrtf(fmaxf(sqi + sqc0 - 2.0f * acc[mt][0][r], 0.0f));
            const float d1 = sqrtf(fmaxf(sqi + sqc1 - 2.0f * acc[mt][1][r], 0.0f));
            __builtin_nontemporal_store(d0, dist + (size_t)grow * N + gc0);
            __builtin_nontemporal_store(d1, dist + (size_t)grow * N + gc1);
            const int tr = (int)((pb_0 >> row_l) & 1) | ((int)((pb_1 >> row_l) & 1) << 1);
            mx0 = fmaxf(mx0, (tr == tc0) ? d0 : 0.0f);
            mg0 = fminf(mg0, (tr >  tc0) ? d0 : BIG);
            ml0 = fminf(ml0, (tr <  tc0) ? d0 : BIG);
            mx1 = fmaxf(mx1, (tr == tc1) ? d1 : 0.0f);
            mg1 = fminf(mg1, (tr >  tc1) ? d1 : BIG);
            ml1 = fminf(ml1, (tr <  tc1) ? d1 : BIG);
        }
    }
    // combine the two hi-halves (each reduced 32 of the 64 rows)
    mx0 = fmaxf(mx0, __shfl_xor(mx0, 32));
    mg0 = fminf(mg0, __shfl_xor(mg0, 32));
    ml0 = fminf(ml0, __shfl_xor(ml0, 32));
    mx1 = fmaxf(mx1, __shfl_xor(mx1, 32));
    mg1 = fminf(mg1, __shfl_xor(mg1, 32));
    ml1 = fminf(ml1, __shfl_xor(ml1, 32));

    if (hi == 0) {
        atomicMaxFloatPos(&ap[gc0],  mx0);
        atomicMinFloatPos(&ang[gc0], mg0);
        atomicMinFloatPos(&anl[gc0], ml0);
        atomicMaxFloatPos(&ap[gc1],  mx1);
        atomicMinFloatPos(&ang[gc1], mg1);
        atomicMinFloatPos(&anl[gc1], ml1);
    }
}

// One block: histogram (packed wave reduce), then loss/cnt, write outputs.
__global__ __launch_bounds__(1024) void finish_kernel(const float* __restrict__ ap,
                                                      const float* __restrict__ ang,
                                                      const float* __restrict__ anl,
                                                      const int* __restrict__ tgt,
                                                      float* __restrict__ out) {
    __shared__ int hist[4];
    __shared__ unsigned hsum[2][16];
    __shared__ float wsum[16];
    __shared__ int wcnt[16];
    const int tid = threadIdx.x, lane = tid & 63, wv = tid >> 6;

    const int4 t4 = *(const int4*)&tgt[tid * 4];
    int c[4] = {0, 0, 0, 0};
    c[t4.x & 3]++; c[t4.y & 3]++; c[t4.z & 3]++; c[t4.w & 3]++;
    unsigned p01 = (unsigned)c[0] | ((unsigned)c[1] << 16);
    unsigned p23 = (unsigned)c[2] | ((unsigned)c[3] << 16);
    #pragma unroll
    for (int off = 32; off; off >>= 1) {
        p01 += __shfl_down(p01, off);
        p23 += __shfl_down(p23, off);
    }
    if (lane == 0) { hsum[0][wv] = p01; hsum[1][wv] = p23; }
    __syncthreads();
    if (tid == 0) {
        unsigned a = 0, b = 0;
        for (int i = 0; i < 16; ++i) { a += hsum[0][i]; b += hsum[1][i]; }
        hist[0] = a & 0xFFFF; hist[1] = a >> 16;
        hist[2] = b & 0xFFFF; hist[3] = b >> 16;
    }
    __syncthreads();

    float term = 0.0f; int cc = 0;
    const int lab[4] = {t4.x & 3, t4.y & 3, t4.z & 3, t4.w & 3};
    #pragma unroll
    for (int j = 0; j < 4; ++j) {
        const int i = tid * 4 + j;
        term += fmaxf(ap[i] - fabsf(ang[i] - anl[i]) + MARGIN, 0.0f);
        cc += (hist[lab[j]] == 1) ? 1 : 0;
    }
    #pragma unroll
    for (int off = 32; off; off >>= 1) {
        term += __shfl_down(term, off);
        cc   += __shfl_down(cc, off);
    }
    if (lane == 0) { wsum[wv] = term; wcnt[wv] = cc; }
    __syncthreads();
    if (tid == 0) {
        float ls = 0.0f; int cs = 0;
        for (int i = 0; i < 16; ++i) { ls += wsum[i]; cs += wcnt[i]; }
        out[0] = ls * (1.0f / N);
        out[1 + (size_t)N * N] = (float)cs;
    }
}

extern "C" void kernel_launch(void* const* d_in, const int* in_sizes, int n_in,
                              void* d_out, int out_size, void* d_ws, size_t ws_size,
                              hipStream_t stream) {
    const float* x   = (const float*)d_in[0];
    const int*   tgt = (const int*)d_in[1];
    float* out = (float*)d_out;
    char*  ws  = (char*)d_ws;

    _Float16* Xf  = (_Float16*)ws;                    // 2 MiB, 16B-aligned
    float*    sq  = (float*)(ws + 2097152);
    float*    ap  = sq + 4096;
    float*    ang = sq + 8192;
    float*    anl = sq + 12288;

    prep_kernel<<<N / 4, 256, 0, stream>>>(x, sq, Xf, ap, ang, anl);
    dim3 grid(N / 256, N / 128);                      // 16 x 32 = 512 blocks
    dist_kernel<<<grid, 512, 0, stream>>>(Xf, tgt, sq, out + 1, ap, ang, anl);
    finish_kernel<<<1, 1024, 0, stream>>>(ap, ang, anl, tgt, out);
}

// Round 8
// 107.621 us; speedup vs baseline: 1.8420x; 1.0350x over previous
//
#include <hip/hip_runtime.h>

#define N 4096
#define D 256
#define MARGIN 0.3f
#define BIG 10000.0f

typedef _Float16 f16x8 __attribute__((ext_vector_type(8)));
typedef _Float16 f16x4 __attribute__((ext_vector_type(4)));
typedef float floatx16 __attribute__((ext_vector_type(16)));

__device__ inline void atomicMaxFloatPos(float* a, float v) {
    atomicMax((int*)a, __float_as_int(v));   // valid: all values >= 0
}
__device__ inline void atomicMinFloatPos(float* a, float v) {
    atomicMin((int*)a, __float_as_int(v));
}

// async 16B global -> LDS (wave-uniform LDS base + lane*16)
__device__ inline void gl_lds16(const void* g, void* l) {
    __builtin_amdgcn_global_load_lds(
        (const __attribute__((address_space(1))) unsigned int*)g,
        (__attribute__((address_space(3))) unsigned int*)l, 16, 0, 0);
}

// Wave per row: convert x -> fp16 Xf (RNE, row-major), sq from the CONVERTED
// values (so the Gram diagonal cancels exactly), init ap/ang/anl; block 0
// zeroes the two scalar outputs (finish accumulates into them via atomicAdd).
__global__ __launch_bounds__(256) void prep_kernel(const float* __restrict__ x,
                                                   float* __restrict__ sq,
                                                   _Float16* __restrict__ Xf,
                                                   float* ap, float* ang, float* anl,
                                                   float* __restrict__ out) {
    const int wave = threadIdx.x >> 6, lane = threadIdx.x & 63;
    const int row = blockIdx.x * 4 + wave;
    const float4 v = *(const float4*)(x + (size_t)row * D + lane * 4);
    f16x4 h;
    h[0] = (_Float16)v.x; h[1] = (_Float16)v.y;
    h[2] = (_Float16)v.z; h[3] = (_Float16)v.w;
    *(f16x4*)(Xf + (size_t)row * D + lane * 4) = h;
    const float c0 = (float)h[0], c1 = (float)h[1], c2 = (float)h[2], c3 = (float)h[3];
    float s = c0 * c0 + c1 * c1 + c2 * c2 + c3 * c3;
    #pragma unroll
    for (int off = 32; off; off >>= 1) s += __shfl_down(s, off);
    if (lane == 0) sq[row] = s;
    if (threadIdx.x < 4) {
        const int i = blockIdx.x * 4 + threadIdx.x;
        ap[i] = 0.0f; ang[i] = BIG; anl[i] = BIG;
    }
    if (blockIdx.x == 0 && threadIdx.x == 0) {
        out[0] = 0.0f;                       // loss accumulator
        out[1 + (size_t)N * N] = 0.0f;       // cnt accumulator
    }
}

// dist v9: 256x256 tile, 8 waves. DEEP staging pipeline (R7 theory: all prior
// variants kept <=1 DMA stage in flight; per-stage compute << per-stage DMA
// service, so the DMA engine idled at every barrier edge):
//   8 stages of BK=32 in FOUR LDS buffers (128 KB), 3 stages in flight
//   continuously, exactly ONE barrier per stage, counted vmcnt (exact: the
//   K-loop has no other VMEM ops).
// Per buffer (32 KB): 256 rows x 128 B, row r = [A(row0+r) 32-fp16 slice ||
// B(col0+r) 32-fp16 slice]; 16B quad l of row r at phys quad l ^ (r&7)
// (v3-proven conflict-free 128B-row scheme; NOT v2's 64B-row mistake).
// DMA: wave wv issues 4 instrs/stage (rg = wv*4+d covers LDS rows rg*8..+7;
// lane: g=lane>>3, p=lane&7, lq=p^g; lq<4 -> A quad lq, else B quad lq-4).
// Buffer safety with one barrier/stage: at iter-s barrier all waves finished
// compute(s-1) (their ds_reads retired before the MFMAs consumed them), and
// ISSUE(s+3) overwrites buffer (s+3)&3 == (s-1)&3 only after that barrier.
// Wave (wr,wc) = (wv>>2, wv&3) owns a 128x64 sub-tile -> acc[4][2].
// Epilogue: unchanged from v6 (no LDS; anchor = column by symmetry; ballot
// label packs; nontemporal coalesced stores; 6 atomics from lanes 0..31).
__global__ __launch_bounds__(512, 1) void dist_kernel(const _Float16* __restrict__ Xf,
                                                      const int* __restrict__ tgt,
                                                      const float* __restrict__ sq,
                                                      float* __restrict__ dist,
                                                      float* ap, float* ang, float* anl) {
    __shared__ _Float16 lds[65536];         // 128 KiB: 4 stage-buffers x 16384 elems

    const int tid  = threadIdx.x;
    const int wv   = tid >> 6;              // 0..7
    const int lane = tid & 63;
    const int row0 = blockIdx.y * 256;
    const int col0 = blockIdx.x * 256;
    const int wr = wv >> 2, wc = wv & 3;

    // DMA per-lane constants
    const int g = lane >> 3, p = lane & 7, lq = p ^ g;
    const int sel  = (lq < 4 ? row0 : col0) + g;
    const int koff = (lq & 3) * 8;

    const int m0 = lane & 31;
    const int hi = lane >> 5;
    const int sw = m0 & 7;                   // frag swizzle key (all frag rows == m0 mod 8)

    floatx16 acc[4][2];
    #pragma unroll
    for (int mt = 0; mt < 4; ++mt)
        #pragma unroll
        for (int nt = 0; nt < 2; ++nt)
            #pragma unroll
            for (int r = 0; r < 16; ++r) acc[mt][nt][r] = 0.0f;

    // ---- stage DMA issue: 4 x gl_lds16 into buffer (st&3) ----
    #define ISSUE_STAGE(st)                                                       \
    do {                                                                          \
        _Float16* buf_ = lds + ((st) & 3) * 16384;                                \
        const int k0_ = (st) * 32;                                                \
        _Pragma("unroll")                                                         \
        for (int d = 0; d < 4; ++d) {                                             \
            const int rg = wv * 4 + d;                                            \
            gl_lds16(Xf + (size_t)(sel + rg * 8) * D + k0_ + koff,                \
                     buf_ + rg * 512);                                            \
        }                                                                         \
    } while (0)

    ISSUE_STAGE(0);
    ISSUE_STAGE(1);
    ISSUE_STAGE(2);

    #pragma unroll
    for (int s = 0; s < 8; ++s) {
        // wait for stage s's 4 loads; stages s+1,s+2 (8 loads) stay in flight
        if (s < 6)      { __asm__ volatile("s_waitcnt vmcnt(8)" ::: "memory"); }
        else if (s == 6){ __asm__ volatile("s_waitcnt vmcnt(4)" ::: "memory"); }
        else            { __asm__ volatile("s_waitcnt vmcnt(0)" ::: "memory"); }
        __builtin_amdgcn_s_barrier();        // all waves' stage-s data in LDS
        if (s < 5) ISSUE_STAGE(s + 3);       // refill buffer (s-1)&3 (readers done)

        const _Float16* buf = lds + (s & 3) * 16384;
        const _Float16* Ab  = buf + ((size_t)wr * 128 + m0) * 64;
        const _Float16* Bb  = buf + ((size_t)wc * 64  + m0) * 64;

        __builtin_amdgcn_s_setprio(1);
        #pragma unroll
        for (int ks = 0; ks < 2; ++ks) {
            const int la  = ks * 2 + hi;             // 0..3
            const int poa = ((la       ^ sw) << 3);
            const int pob = (((la + 4) ^ sw) << 3);
            f16x8 b0 = *(const f16x8*)(Bb + pob);
            f16x8 b1 = *(const f16x8*)(Bb + 2048 + pob);
            #pragma unroll
            for (int mt = 0; mt < 4; ++mt) {
                f16x8 a = *(const f16x8*)(Ab + mt * 2048 + poa);
                acc[mt][0] = __builtin_amdgcn_mfma_f32_32x32x16_f16(a, b0, acc[mt][0], 0, 0, 0);
                acc[mt][1] = __builtin_amdgcn_mfma_f32_32x32x16_f16(a, b1, acc[mt][1], 0, 0, 0);
            }
        }
        __builtin_amdgcn_s_setprio(0);
        __asm__ volatile("" ::: "memory");   // pin stage ordering
    }
    #undef ISSUE_STAGE

    // ---- Epilogue (v6, unchanged): d = sqrt(sqi + sqj - 2*dot); nontemporal
    // coalesced stores; in-register column reduction (anchor = column).
    // C layout: col = lane&31 (+32*nt), row = (r&3) + 8*(r>>2) + 4*hi + 32*mt.
    const int rowA    = row0 + wr * 128;
    const int colbase = col0 + wc * 64;
    const int tl0 = tgt[rowA + lane];
    const int tl1 = tgt[rowA + 64 + lane];
    const float sqr0 = sq[rowA + lane];
    const float sqr1 = sq[rowA + 64 + lane];
    const unsigned long long pa0 = __ballot(tl0 & 1), pa1 = __ballot(tl0 & 2);
    const unsigned long long pb0 = __ballot(tl1 & 1), pb1 = __ballot(tl1 & 2);
    const int gc0 = colbase + m0, gc1 = colbase + 32 + m0;
    const int tc0 = tgt[gc0], tc1 = tgt[gc1];
    const float sqc0 = sq[gc0], sqc1 = sq[gc1];
    const int rl_base = 4 * hi;

    float mx0 = 0.0f, mg0 = BIG, ml0 = BIG;
    float mx1 = 0.0f, mg1 = BIG, ml1 = BIG;

    #pragma unroll
    for (int mt = 0; mt < 4; ++mt) {
        #pragma unroll
        for (int r = 0; r < 16; ++r) {
            const int row_l = mt * 32 + (r & 3) + 8 * (r >> 2) + rl_base;  // 0..127
            const int rl = row_l & 63;
            const int grow = rowA + row_l;
            const float sqi = __shfl(mt < 2 ? sqr0 : sqr1, rl);
            const float d0 = sqrtf(fmaxf(sqi + sqc0 - 2.0f * acc[mt][0][r], 0.0f));
            const float d1 = sqrtf(fmaxf(sqi + sqc1 - 2.0f * acc[mt][1][r], 0.0f));
            __builtin_nontemporal_store(d0, dist + (size_t)grow * N + gc0);
            __builtin_nontemporal_store(d1, dist + (size_t)grow * N + gc1);
            const unsigned long long q0 = (mt < 2 ? pa0 : pb0);
            const unsigned long long q1 = (mt < 2 ? pa1 : pb1);
            const int tr = (int)((q0 >> rl) & 1) | ((int)((q1 >> rl) & 1) << 1);
            mx0 = fmaxf(mx0, (tr == tc0) ? d0 : 0.0f);
            mg0 = fminf(mg0, (tr >  tc0) ? d0 : BIG);
            ml0 = fminf(ml0, (tr <  tc0) ? d0 : BIG);
            mx1 = fmaxf(mx1, (tr == tc1) ? d1 : 0.0f);
            mg1 = fminf(mg1, (tr >  tc1) ? d1 : BIG);
            ml1 = fminf(ml1, (tr <  tc1) ? d1 : BIG);
        }
    }
    // combine the two hi-halves (each reduced 64 of the 128 rows)
    mx0 = fmaxf(mx0, __shfl_xor(mx0, 32));
    mg0 = fminf(mg0, __shfl_xor(mg0, 32));
    ml0 = fminf(ml0, __shfl_xor(ml0, 32));
    mx1 = fmaxf(mx1, __shfl_xor(mx1, 32));
    mg1 = fminf(mg1, __shfl_xor(mg1, 32));
    ml1 = fminf(ml1, __shfl_xor(ml1, 32));

    if (hi == 0) {
        atomicMaxFloatPos(&ap[gc0],  mx0);
        atomicMinFloatPos(&ang[gc0], mg0);
        atomicMinFloatPos(&anl[gc0], ml0);
        atomicMaxFloatPos(&ap[gc1],  mx1);
        atomicMinFloatPos(&ang[gc1], mg1);
        atomicMinFloatPos(&anl[gc1], ml1);
    }
}

// Parallel finish: 16 blocks x 256 threads. Each block recomputes the global
// label histogram from tgt (16 KB, L2-hot), then handles 256 rows; partial
// loss/cnt accumulated into out via atomicAdd (prep zeroed the accumulators).
__global__ __launch_bounds__(256) void finish_kernel(const float* __restrict__ ap,
                                                     const float* __restrict__ ang,
                                                     const float* __restrict__ anl,
                                                     const int* __restrict__ tgt,
                                                     float* __restrict__ out) {
    __shared__ unsigned hs01[4], hs23[4];
    __shared__ float fs[4];
    __shared__ int   cs[4];
    const int tid = threadIdx.x, lane = tid & 63, wv = tid >> 6;

    // global histogram (every block recomputes; 4096 labels, int4 loads)
    int c[4] = {0, 0, 0, 0};
    #pragma unroll
    for (int j = 0; j < 4; ++j) {
        const int4 t4 = *(const int4*)&tgt[(j * 256 + tid) * 4];
        c[t4.x & 3]++; c[t4.y & 3]++; c[t4.z & 3]++; c[t4.w & 3]++;
    }
    unsigned p01 = (unsigned)c[0] | ((unsigned)c[1] << 16);
    unsigned p23 = (unsigned)c[2] | ((unsigned)c[3] << 16);
    #pragma unroll
    for (int off = 32; off; off >>= 1) {
        p01 += __shfl_down(p01, off);
        p23 += __shfl_down(p23, off);
    }
    if (lane == 0) { hs01[wv] = p01; hs23[wv] = p23; }
    __syncthreads();
    const unsigned a = hs01[0] + hs01[1] + hs01[2] + hs01[3];
    const unsigned b = hs23[0] + hs23[1] + hs23[2] + hs23[3];
    const int h0 = a & 0xFFFF, h1 = a >> 16, h2 = b & 0xFFFF, h3 = b >> 16;

    // per-row term + cnt
    const int row = blockIdx.x * 256 + tid;
    const int t = tgt[row] & 3;
    float term = fmaxf(ap[row] - fabsf(ang[row] - anl[row]) + MARGIN, 0.0f);
    const int h = (t == 0) ? h0 : (t == 1) ? h1 : (t == 2) ? h2 : h3;
    int cc = (h == 1) ? 1 : 0;

    #pragma unroll
    for (int off = 32; off; off >>= 1) {
        term += __shfl_down(term, off);
        cc   += __shfl_down(cc, off);
    }
    if (lane == 0) { fs[wv] = term; cs[wv] = cc; }
    __syncthreads();
    if (tid == 0) {
        const float ls = fs[0] + fs[1] + fs[2] + fs[3];
        const int   csum = cs[0] + cs[1] + cs[2] + cs[3];
        atomicAdd(&out[0], ls * (1.0f / N));
        atomicAdd(&out[1 + (size_t)N * N], (float)csum);
    }
}

extern "C" void kernel_launch(void* const* d_in, const int* in_sizes, int n_in,
                              void* d_out, int out_size, void* d_ws, size_t ws_size,
                              hipStream_t stream) {
    const float* x   = (const float*)d_in[0];
    const int*   tgt = (const int*)d_in[1];
    float* out = (float*)d_out;
    char*  ws  = (char*)d_ws;

    _Float16* Xf  = (_Float16*)ws;                    // 2 MiB, 16B-aligned
    float*    sq  = (float*)(ws + 2097152);
    float*    ap  = sq + 4096;
    float*    ang = sq + 8192;
    float*    anl = sq + 12288;

    prep_kernel<<<N / 4, 256, 0, stream>>>(x, sq, Xf, ap, ang, anl, out);
    dim3 grid(N / 256, N / 256);                      // 16 x 16 = 256 blocks
    dist_kernel<<<grid, 512, 0, stream>>>(Xf, tgt, sq, out + 1, ap, ang, anl);
    finish_kernel<<<16, 256, 0, stream>>>(ap, ang, anl, tgt, out);
}

// Round 9
// 102.337 us; speedup vs baseline: 1.9371x; 1.0516x over previous
//
#include <hip/hip_runtime.h>

#define N 4096
#define D 256
#define MARGIN 0.3f
#define BIG 10000.0f

typedef _Float16 f16x8 __attribute__((ext_vector_type(8)));
typedef _Float16 f16x4 __attribute__((ext_vector_type(4)));
typedef float floatx16 __attribute__((ext_vector_type(16)));

__device__ inline void atomicMaxFloatPos(float* a, float v) {
    atomicMax((int*)a, __float_as_int(v));   // valid: all values >= 0
}
__device__ inline void atomicMinFloatPos(float* a, float v) {
    atomicMin((int*)a, __float_as_int(v));
}

// async 16B global -> LDS (wave-uniform LDS base + lane*16)
__device__ inline void gl_lds16(const void* g, void* l) {
    __builtin_amdgcn_global_load_lds(
        (const __attribute__((address_space(1))) unsigned int*)g,
        (__attribute__((address_space(3))) unsigned int*)l, 16, 0, 0);
}

// Wave per row: convert x -> fp16 Xf (RNE, row-major), sq from the CONVERTED
// values (so the Gram diagonal cancels exactly), init ap/ang/anl; block 0
// zeroes the two scalar outputs (finish accumulates into them via atomicAdd).
__global__ __launch_bounds__(256) void prep_kernel(const float* __restrict__ x,
                                                   float* __restrict__ sq,
                                                   _Float16* __restrict__ Xf,
                                                   float* ap, float* ang, float* anl,
                                                   float* __restrict__ out) {
    const int wave = threadIdx.x >> 6, lane = threadIdx.x & 63;
    const int row = blockIdx.x * 4 + wave;
    const float4 v = *(const float4*)(x + (size_t)row * D + lane * 4);
    f16x4 h;
    h[0] = (_Float16)v.x; h[1] = (_Float16)v.y;
    h[2] = (_Float16)v.z; h[3] = (_Float16)v.w;
    *(f16x4*)(Xf + (size_t)row * D + lane * 4) = h;
    const float c0 = (float)h[0], c1 = (float)h[1], c2 = (float)h[2], c3 = (float)h[3];
    float s = c0 * c0 + c1 * c1 + c2 * c2 + c3 * c3;
    #pragma unroll
    for (int off = 32; off; off >>= 1) s += __shfl_down(s, off);
    if (lane == 0) sq[row] = s;
    if (threadIdx.x < 4) {
        const int i = blockIdx.x * 4 + threadIdx.x;
        ap[i] = 0.0f; ang[i] = BIG; anl[i] = BIG;
    }
    if (blockIdx.x == 0 && threadIdx.x == 0) {
        out[0] = 0.0f;                       // loss accumulator
        out[1 + (size_t)N * N] = 0.0f;       // cnt accumulator
    }
}

// dist v10 == v9 with ONE change: PLAIN cached stores instead of
// __builtin_nontemporal_store. Evidence (R8 post-mortem): harness fill writes
// 268 MB with plain stores at 6.1 TB/s; every dist variant with nt stores is
// pinned at 1.8-2.1 TB/s total BW regardless of traffic volume (v7 tripled
// traffic, rate constant) -> the nt write path itself is rate-limited.
// Structure (v9): 256x256 tile, 8 waves, deep staging pipeline: 8 stages of
// BK=32 in FOUR LDS buffers (128 KB), 3 stages in flight, one barrier/stage,
// counted vmcnt (exact: the K-loop has no other VMEM ops).
// Per buffer (32 KB): 256 rows x 128 B, row r = [A(row0+r) 32-fp16 slice ||
// B(col0+r) 32-fp16 slice]; 16B quad l of row r at phys quad l ^ (r&7).
// Wave (wr,wc) = (wv>>2, wv&3) owns a 128x64 sub-tile -> acc[4][2].
// Epilogue: no LDS; anchor = column (valid by symmetry); ballot label packs;
// coalesced stores; 6 atomics from lanes 0..31.
__global__ __launch_bounds__(512, 1) void dist_kernel(const _Float16* __restrict__ Xf,
                                                      const int* __restrict__ tgt,
                                                      const float* __restrict__ sq,
                                                      float* __restrict__ dist,
                                                      float* ap, float* ang, float* anl) {
    __shared__ _Float16 lds[65536];         // 128 KiB: 4 stage-buffers x 16384 elems

    const int tid  = threadIdx.x;
    const int wv   = tid >> 6;              // 0..7
    const int lane = tid & 63;
    const int row0 = blockIdx.y * 256;
    const int col0 = blockIdx.x * 256;
    const int wr = wv >> 2, wc = wv & 3;

    // DMA per-lane constants
    const int g = lane >> 3, p = lane & 7, lq = p ^ g;
    const int sel  = (lq < 4 ? row0 : col0) + g;
    const int koff = (lq & 3) * 8;

    const int m0 = lane & 31;
    const int hi = lane >> 5;
    const int sw = m0 & 7;                   // frag swizzle key (all frag rows == m0 mod 8)

    floatx16 acc[4][2];
    #pragma unroll
    for (int mt = 0; mt < 4; ++mt)
        #pragma unroll
        for (int nt = 0; nt < 2; ++nt)
            #pragma unroll
            for (int r = 0; r < 16; ++r) acc[mt][nt][r] = 0.0f;

    // ---- stage DMA issue: 4 x gl_lds16 into buffer (st&3) ----
    #define ISSUE_STAGE(st)                                                       \
    do {                                                                          \
        _Float16* buf_ = lds + ((st) & 3) * 16384;                                \
        const int k0_ = (st) * 32;                                                \
        _Pragma("unroll")                                                         \
        for (int d = 0; d < 4; ++d) {                                             \
            const int rg = wv * 4 + d;                                            \
            gl_lds16(Xf + (size_t)(sel + rg * 8) * D + k0_ + koff,                \
                     buf_ + rg * 512);                                            \
        }                                                                         \
    } while (0)

    ISSUE_STAGE(0);
    ISSUE_STAGE(1);
    ISSUE_STAGE(2);

    #pragma unroll
    for (int s = 0; s < 8; ++s) {
        // wait for stage s's 4 loads; stages s+1,s+2 (8 loads) stay in flight
        if (s < 6)      { __asm__ volatile("s_waitcnt vmcnt(8)" ::: "memory"); }
        else if (s == 6){ __asm__ volatile("s_waitcnt vmcnt(4)" ::: "memory"); }
        else            { __asm__ volatile("s_waitcnt vmcnt(0)" ::: "memory"); }
        __builtin_amdgcn_s_barrier();        // all waves' stage-s data in LDS
        if (s < 5) ISSUE_STAGE(s + 3);       // refill buffer (s-1)&3 (readers done)

        const _Float16* buf = lds + (s & 3) * 16384;
        const _Float16* Ab  = buf + ((size_t)wr * 128 + m0) * 64;
        const _Float16* Bb  = buf + ((size_t)wc * 64  + m0) * 64;

        __builtin_amdgcn_s_setprio(1);
        #pragma unroll
        for (int ks = 0; ks < 2; ++ks) {
            const int la  = ks * 2 + hi;             // 0..3
            const int poa = ((la       ^ sw) << 3);
            const int pob = (((la + 4) ^ sw) << 3);
            f16x8 b0 = *(const f16x8*)(Bb + pob);
            f16x8 b1 = *(const f16x8*)(Bb + 2048 + pob);
            #pragma unroll
            for (int mt = 0; mt < 4; ++mt) {
                f16x8 a = *(const f16x8*)(Ab + mt * 2048 + poa);
                acc[mt][0] = __builtin_amdgcn_mfma_f32_32x32x16_f16(a, b0, acc[mt][0], 0, 0, 0);
                acc[mt][1] = __builtin_amdgcn_mfma_f32_32x32x16_f16(a, b1, acc[mt][1], 0, 0, 0);
            }
        }
        __builtin_amdgcn_s_setprio(0);
        __asm__ volatile("" ::: "memory");   // pin stage ordering
    }
    #undef ISSUE_STAGE

    // ---- Epilogue: d = sqrt(sqi + sqj - 2*dot); PLAIN coalesced stores
    // (the isolated change vs v9); in-register column reduction (anchor = col).
    // C layout: col = lane&31 (+32*nt), row = (r&3) + 8*(r>>2) + 4*hi + 32*mt.
    const int rowA    = row0 + wr * 128;
    const int colbase = col0 + wc * 64;
    const int tl0 = tgt[rowA + lane];
    const int tl1 = tgt[rowA + 64 + lane];
    const float sqr0 = sq[rowA + lane];
    const float sqr1 = sq[rowA + 64 + lane];
    const unsigned long long pa0 = __ballot(tl0 & 1), pa1 = __ballot(tl0 & 2);
    const unsigned long long pb0 = __ballot(tl1 & 1), pb1 = __ballot(tl1 & 2);
    const int gc0 = colbase + m0, gc1 = colbase + 32 + m0;
    const int tc0 = tgt[gc0], tc1 = tgt[gc1];
    const float sqc0 = sq[gc0], sqc1 = sq[gc1];
    const int rl_base = 4 * hi;

    float mx0 = 0.0f, mg0 = BIG, ml0 = BIG;
    float mx1 = 0.0f, mg1 = BIG, ml1 = BIG;

    #pragma unroll
    for (int mt = 0; mt < 4; ++mt) {
        #pragma unroll
        for (int r = 0; r < 16; ++r) {
            const int row_l = mt * 32 + (r & 3) + 8 * (r >> 2) + rl_base;  // 0..127
            const int rl = row_l & 63;
            const int grow = rowA + row_l;
            const float sqi = __shfl(mt < 2 ? sqr0 : sqr1, rl);
            const float d0 = sqrtf(fmaxf(sqi + sqc0 - 2.0f * acc[mt][0][r], 0.0f));
            const float d1 = sqrtf(fmaxf(sqi + sqc1 - 2.0f * acc[mt][1][r], 0.0f));
            dist[(size_t)grow * N + gc0] = d0;
            dist[(size_t)grow * N + gc1] = d1;
            const unsigned long long q0 = (mt < 2 ? pa0 : pb0);
            const unsigned long long q1 = (mt < 2 ? pa1 : pb1);
            const int tr = (int)((q0 >> rl) & 1) | ((int)((q1 >> rl) & 1) << 1);
            mx0 = fmaxf(mx0, (tr == tc0) ? d0 : 0.0f);
            mg0 = fminf(mg0, (tr >  tc0) ? d0 : BIG);
            ml0 = fminf(ml0, (tr <  tc0) ? d0 : BIG);
            mx1 = fmaxf(mx1, (tr == tc1) ? d1 : 0.0f);
            mg1 = fminf(mg1, (tr >  tc1) ? d1 : BIG);
            ml1 = fminf(ml1, (tr <  tc1) ? d1 : BIG);
        }
    }
    // combine the two hi-halves (each reduced 64 of the 128 rows)
    mx0 = fmaxf(mx0, __shfl_xor(mx0, 32));
    mg0 = fminf(mg0, __shfl_xor(mg0, 32));
    ml0 = fminf(ml0, __shfl_xor(ml0, 32));
    mx1 = fmaxf(mx1, __shfl_xor(mx1, 32));
    mg1 = fminf(mg1, __shfl_xor(mg1, 32));
    ml1 = fminf(ml1, __shfl_xor(ml1, 32));

    if (hi == 0) {
        atomicMaxFloatPos(&ap[gc0],  mx0);
        atomicMinFloatPos(&ang[gc0], mg0);
        atomicMinFloatPos(&anl[gc0], ml0);
        atomicMaxFloatPos(&ap[gc1],  mx1);
        atomicMinFloatPos(&ang[gc1], mg1);
        atomicMinFloatPos(&anl[gc1], ml1);
    }
}

// Parallel finish: 16 blocks x 256 threads. Each block recomputes the global
// label histogram from tgt (16 KB, L2-hot), then handles 256 rows; partial
// loss/cnt accumulated into out via atomicAdd (prep zeroed the accumulators).
__global__ __launch_bounds__(256) void finish_kernel(const float* __restrict__ ap,
                                                     const float* __restrict__ ang,
                                                     const float* __restrict__ anl,
                                                     const int* __restrict__ tgt,
                                                     float* __restrict__ out) {
    __shared__ unsigned hs01[4], hs23[4];
    __shared__ float fs[4];
    __shared__ int   cs[4];
    const int tid = threadIdx.x, lane = tid & 63, wv = tid >> 6;

    // global histogram (every block recomputes; 4096 labels, int4 loads)
    int c[4] = {0, 0, 0, 0};
    #pragma unroll
    for (int j = 0; j < 4; ++j) {
        const int4 t4 = *(const int4*)&tgt[(j * 256 + tid) * 4];
        c[t4.x & 3]++; c[t4.y & 3]++; c[t4.z & 3]++; c[t4.w & 3]++;
    }
    unsigned p01 = (unsigned)c[0] | ((unsigned)c[1] << 16);
    unsigned p23 = (unsigned)c[2] | ((unsigned)c[3] << 16);
    #pragma unroll
    for (int off = 32; off; off >>= 1) {
        p01 += __shfl_down(p01, off);
        p23 += __shfl_down(p23, off);
    }
    if (lane == 0) { hs01[wv] = p01; hs23[wv] = p23; }
    __syncthreads();
    const unsigned a = hs01[0] + hs01[1] + hs01[2] + hs01[3];
    const unsigned b = hs23[0] + hs23[1] + hs23[2] + hs23[3];
    const int h0 = a & 0xFFFF, h1 = a >> 16, h2 = b & 0xFFFF, h3 = b >> 16;

    // per-row term + cnt
    const int row = blockIdx.x * 256 + tid;
    const int t = tgt[row] & 3;
    float term = fmaxf(ap[row] - fabsf(ang[row] - anl[row]) + MARGIN, 0.0f);
    const int h = (t == 0) ? h0 : (t == 1) ? h1 : (t == 2) ? h2 : h3;
    int cc = (h == 1) ? 1 : 0;

    #pragma unroll
    for (int off = 32; off; off >>= 1) {
        term += __shfl_down(term, off);
        cc   += __shfl_down(cc, off);
    }
    if (lane == 0) { fs[wv] = term; cs[wv] = cc; }
    __syncthreads();
    if (tid == 0) {
        const float ls = fs[0] + fs[1] + fs[2] + fs[3];
        const int   csum = cs[0] + cs[1] + cs[2] + cs[3];
        atomicAdd(&out[0], ls * (1.0f / N));
        atomicAdd(&out[1 + (size_t)N * N], (float)csum);
    }
}

extern "C" void kernel_launch(void* const* d_in, const int* in_sizes, int n_in,
                              void* d_out, int out_size, void* d_ws, size_t ws_size,
                              hipStream_t stream) {
    const float* x   = (const float*)d_in[0];
    const int*   tgt = (const int*)d_in[1];
    float* out = (float*)d_out;
    char*  ws  = (char*)d_ws;

    _Float16* Xf  = (_Float16*)ws;                    // 2 MiB, 16B-aligned
    float*    sq  = (float*)(ws + 2097152);
    float*    ap  = sq + 4096;
    float*    ang = sq + 8192;
    float*    anl = sq + 12288;

    prep_kernel<<<N / 4, 256, 0, stream>>>(x, sq, Xf, ap, ang, anl, out);
    dim3 grid(N / 256, N / 256);                      // 16 x 16 = 256 blocks
    dist_kernel<<<grid, 512, 0, stream>>>(Xf, tgt, sq, out + 1, ap, ang, anl);
    finish_kernel<<<16, 256, 0, stream>>>(ap, ang, anl, tgt, out);
}